// Round 1
// baseline (216.715 us; speedup 1.0000x reference)
//
#include <hip/hip_runtime.h>
#include <math.h>

#define NE 64
#define ND 32
#define NH 4
#define NHD 8
#define NTASK 6
#define BLK 256

// ---------------------------------------------------------------------------
// Kernel A: per-task precompute (6 x 64 tables), all in double precision.
// cl = expert_weight @ fc_gate_w.T + fc_gate_b
// ns = softplus(expert_weight @ fc_noise_w.T + fc_noise_b) + 0.01
// ---------------------------------------------------------------------------
__global__ void precompute_kernel(
    const float* __restrict__ embed_table,   // (6,32)
    const float* __restrict__ expert_keys,   // (32,32)
    const float* __restrict__ in_proj_w,     // (96,32)
    const float* __restrict__ in_proj_b,     // (96,)
    const float* __restrict__ fc_gate_w,     // (64,32)
    const float* __restrict__ fc_gate_b,     // (64,)
    const float* __restrict__ fc_noise_w,    // (64,32)
    const float* __restrict__ fc_noise_b,    // (64,)
    double* __restrict__ cl_d, double* __restrict__ ns_d,   // (6*64)
    float*  __restrict__ cl_f, float*  __restrict__ ns_f)   // (6*64)
{
    __shared__ double Ksh[32][32];   // K[s][j]
    __shared__ double Qsh[6][32];    // Q[t][j]
    __shared__ double sc[6][4][32];  // scores / probs
    __shared__ double attn[6][32];
    __shared__ double ew[6][32];
    const int tid = threadIdx.x;

    // K = expert_keys @ Wk.T + bk   (Wk = in_proj_w[32:64])
    for (int idx = tid; idx < 32 * 32; idx += BLK) {
        int s = idx >> 5, j = idx & 31;
        double acc = (double)in_proj_b[32 + j];
        for (int d = 0; d < 32; ++d)
            acc += (double)expert_keys[s * 32 + d] * (double)in_proj_w[(32 + j) * 32 + d];
        Ksh[s][j] = acc;
    }
    // Q = x @ Wq.T + bq  (x = embed_table rows, Wq = in_proj_w[0:32])
    for (int idx = tid; idx < NTASK * 32; idx += BLK) {
        int t = idx >> 5, j = idx & 31;
        double acc = (double)in_proj_b[j];
        for (int d = 0; d < 32; ++d)
            acc += (double)embed_table[t * 32 + d] * (double)in_proj_w[j * 32 + d];
        Qsh[t][j] = acc;
    }
    __syncthreads();

    // scores[t][h][s] = dot(Q[t][h*8:..], K[s][h*8:..]) / sqrt(8)  (f32-rounded const)
    const double SCALE = 1.0 / (double)((float)2.8284271247461903);
    for (int idx = tid; idx < NTASK * 4 * 32; idx += BLK) {
        int t = idx >> 7, h = (idx >> 5) & 3, s = idx & 31;
        double acc = 0.0;
        for (int d = 0; d < NHD; ++d)
            acc += Qsh[t][h * NHD + d] * Ksh[s][h * NHD + d];
        sc[t][h][s] = acc * SCALE;
    }
    __syncthreads();

    // softmax over s per (t,h), in place
    if (tid < NTASK * 4) {
        int t = tid >> 2, h = tid & 3;
        double m = sc[t][h][0];
        for (int s = 1; s < 32; ++s) m = fmax(m, sc[t][h][s]);
        double sum = 0.0;
        for (int s = 0; s < 32; ++s) { double e0 = exp(sc[t][h][s] - m); sc[t][h][s] = e0; sum += e0; }
        double inv = 1.0 / sum;
        for (int s = 0; s < 32; ++s) sc[t][h][s] *= inv;
    }
    __syncthreads();

    // attn = mean over h; expert_weight = softmax over s
    if (tid < NTASK) {
        int t = tid;
        double m = -1e300;
        for (int s = 0; s < 32; ++s) {
            double a = (sc[t][0][s] + sc[t][1][s] + sc[t][2][s] + sc[t][3][s]) * 0.25;
            attn[t][s] = a;
            m = fmax(m, a);
        }
        double sum = 0.0;
        for (int s = 0; s < 32; ++s) { double e0 = exp(attn[t][s] - m); ew[t][s] = e0; sum += e0; }
        double inv = 1.0 / sum;
        for (int s = 0; s < 32; ++s) ew[t][s] *= inv;
    }
    __syncthreads();

    // cl / ns tables
    for (int idx = tid; idx < NTASK * NE; idx += BLK) {
        int t = idx >> 6, e = idx & 63;
        double a  = (double)fc_gate_b[e];
        double n0 = (double)fc_noise_b[e];
        for (int d = 0; d < 32; ++d) {
            double w = ew[t][d];
            a  += w * (double)fc_gate_w [e * 32 + d];
            n0 += w * (double)fc_noise_w[e * 32 + d];
        }
        double sp = (n0 > 0.0) ? (n0 + log1p(exp(-n0))) : log1p(exp(n0));
        double ns = sp + 0.01;
        cl_d[idx] = a;
        ns_d[idx] = ns;
        cl_f[idx] = (float)a;
        ns_f[idx] = (float)ns;
    }
}

// ---------------------------------------------------------------------------
// Kernel B: per-token top-2 routing. One token per thread.
// f32 prepass finds top-3 candidates; f64 refine orders them exactly.
// ---------------------------------------------------------------------------
__global__ __launch_bounds__(BLK) void router_kernel(
    const int*   __restrict__ taskID,
    const float* __restrict__ noise,       // (B,64)
    const double* __restrict__ cl_d, const double* __restrict__ ns_d,
    const float*  __restrict__ cl_f, const float*  __restrict__ ns_f,
    float* __restrict__ gates,             // (B,64)
    float* __restrict__ load,              // (64,)
    int B)
{
    // tables laid out [e][t] with stride 8 so per-lane task-dependent reads
    // land in distinct banks (lanes differ only in t -> consecutive slots)
    __shared__ float  s_clf[NE * 8], s_nsf[NE * 8];
    __shared__ double s_cld[NE * 8], s_nsd[NE * 8];
    __shared__ float  s_load[NE];

    const int tid = threadIdx.x;
    for (int i = tid; i < NTASK * NE; i += BLK) {
        int t = i >> 6, e = i & 63;
        s_clf[e * 8 + t] = cl_f[i];
        s_nsf[e * 8 + t] = ns_f[i];
        s_cld[e * 8 + t] = cl_d[i];
        s_nsd[e * 8 + t] = ns_d[i];
    }
    if (tid < NE) s_load[tid] = 0.f;
    __syncthreads();

    const int b = blockIdx.x * BLK + tid;
    if (b < B) {
        const int t = taskID[b];
        const float4* nrow = (const float4*)(noise + (size_t)b * NE);

        float v1 = -INFINITY, v2 = -INFINITY, v3 = -INFINITY;
        int   i1 = 0, i2 = 0, i3 = 0;
        float n1 = 0.f, n2 = 0.f, n3 = 0.f;

        #pragma unroll
        for (int k = 0; k < 16; ++k) {
            float4 nv = nrow[k];
            float na[4] = {nv.x, nv.y, nv.z, nv.w};
            #pragma unroll
            for (int j = 0; j < 4; ++j) {
                const int e = k * 4 + j;
                // match np elementwise: round mul then add (no fma contraction)
                const float l = __fadd_rn(s_clf[e * 8 + t], __fmul_rn(na[j], s_nsf[e * 8 + t]));
                if (l > v1) {
                    v3 = v2; i3 = i2; n3 = n2;
                    v2 = v1; i2 = i1; n2 = n1;
                    v1 = l;  i1 = e;  n1 = na[j];
                } else if (l > v2) {
                    v3 = v2; i3 = i2; n3 = n2;
                    v2 = l;  i2 = e;  n2 = na[j];
                } else if (l > v3) {
                    v3 = l;  i3 = e;  n3 = na[j];
                }
            }
        }

        // f64 refine of the 3 candidates
        double va = s_cld[i1 * 8 + t] + (double)n1 * s_nsd[i1 * 8 + t]; int ia = i1;
        double vb = s_cld[i2 * 8 + t] + (double)n2 * s_nsd[i2 * 8 + t]; int ib = i2;
        double vc = s_cld[i3 * 8 + t] + (double)n3 * s_nsd[i3 * 8 + t]; int ic = i3;
        // sort network (desc by value, tie -> lower index)
        if (vb > va || (vb == va && ib < ia)) { double tv = va; va = vb; vb = tv; int ti = ia; ia = ib; ib = ti; }
        if (vc > va || (vc == va && ic < ia)) { double tv = va; va = vc; vc = tv; int ti = ia; ia = ic; ic = ti; }
        if (vc > vb || (vc == vb && ic < ib)) { double tv = vb; vb = vc; vc = tv; int ti = ib; ib = ic; ic = ti; }

        // 2-way softmax in double
        const double e2 = exp(vb - va);
        const double denom = 1.0 + e2;
        const float g1 = (float)(1.0 / denom);
        const float g2 = (float)(e2 / denom);

        float4* grow = (float4*)(gates + (size_t)b * NE);
        #pragma unroll
        for (int k = 0; k < 16; ++k) {
            const int e0 = k * 4;
            float4 w;
            w.x = (e0 + 0 == ia) ? g1 : ((e0 + 0 == ib) ? g2 : 0.f);
            w.y = (e0 + 1 == ia) ? g1 : ((e0 + 1 == ib) ? g2 : 0.f);
            w.z = (e0 + 2 == ia) ? g1 : ((e0 + 2 == ib) ? g2 : 0.f);
            w.w = (e0 + 3 == ia) ? g1 : ((e0 + 3 == ib) ? g2 : 0.f);
            grow[k] = w;
        }

        atomicAdd(&s_load[ia], g1);
        atomicAdd(&s_load[ib], g2);
    }
    __syncthreads();
    if (tid < NE) atomicAdd(&load[tid], s_load[tid]);
}

// ---------------------------------------------------------------------------
extern "C" void kernel_launch(void* const* d_in, const int* in_sizes, int n_in,
                              void* d_out, int out_size, void* d_ws, size_t ws_size,
                              hipStream_t stream) {
    const int*   taskID      = (const int*)  d_in[0];
    const float* embed_table = (const float*)d_in[1];
    const float* expert_keys = (const float*)d_in[2];
    const float* in_proj_w   = (const float*)d_in[3];
    const float* in_proj_b   = (const float*)d_in[4];
    const float* fc_gate_w   = (const float*)d_in[5];
    const float* fc_gate_b   = (const float*)d_in[6];
    const float* fc_noise_w  = (const float*)d_in[7];
    const float* fc_noise_b  = (const float*)d_in[8];
    const float* noise       = (const float*)d_in[9];

    const int B = in_sizes[0];

    double* cl_d = (double*)d_ws;
    double* ns_d = cl_d + NTASK * NE;
    float*  cl_f = (float*)(ns_d + NTASK * NE);
    float*  ns_f = cl_f + NTASK * NE;

    float* gates = (float*)d_out;
    float* load  = gates + (size_t)B * NE;

    precompute_kernel<<<1, BLK, 0, stream>>>(embed_table, expert_keys, in_proj_w, in_proj_b,
                                             fc_gate_w, fc_gate_b, fc_noise_w, fc_noise_b,
                                             cl_d, ns_d, cl_f, ns_f);
    hipMemsetAsync(load, 0, NE * sizeof(float), stream);

    const int grid = (B + BLK - 1) / BLK;
    router_kernel<<<grid, BLK, 0, stream>>>(taskID, noise, cl_d, ns_d, cl_f, ns_f,
                                            gates, load, B);
}

// Round 2
// 139.800 us; speedup vs baseline: 1.5502x; 1.5502x over previous
//
#include <hip/hip_runtime.h>
#include <math.h>

#define NE 64
#define NTASK 6
#define BLK 256
#define TILE 256   // rows per block (== block size, one row per thread)

// ---------------------------------------------------------------------------
// Kernel A: per-task precompute (6 x 64 tables), all in double precision.
// Outputs packed for the router:
//   tab_f[(e*8+t)*2 + {0,1}] = {clean_logit, noise_std} as f32
//   tab_d[ e*8+t ]           = {clean_logit, noise_std} as double2
// Also zeroes the 64-float `load` output (saves a memset dispatch).
// ---------------------------------------------------------------------------
__global__ void precompute_kernel(
    const float* __restrict__ embed_table,   // (6,32)
    const float* __restrict__ expert_keys,   // (32,32)
    const float* __restrict__ in_proj_w,     // (96,32)
    const float* __restrict__ in_proj_b,     // (96,)
    const float* __restrict__ fc_gate_w,     // (64,32)
    const float* __restrict__ fc_gate_b,     // (64,)
    const float* __restrict__ fc_noise_w,    // (64,32)
    const float* __restrict__ fc_noise_b,    // (64,)
    float*   __restrict__ tab_f,             // 1024 floats
    double2* __restrict__ tab_d,             // 512 double2
    float*   __restrict__ load)              // (64,) zero-init
{
    __shared__ double Ksh[32][32];   // K[s][j]
    __shared__ double Qsh[6][32];    // Q[t][j]
    __shared__ double sc[24][32];    // scores (t*4+h, s) -> exp probs
    __shared__ double attn[6][32];
    __shared__ double ew[6][32];
    __shared__ double red[24];       // per-(t,h) max, then inv-sum
    __shared__ double red2[6];       // per-t max, then inv-sum
    const int tid = threadIdx.x;

    if (tid < NE) load[tid] = 0.f;

    // K = expert_keys @ Wk.T + bk   (Wk = in_proj_w[32:64])
    for (int idx = tid; idx < 32 * 32; idx += BLK) {
        int s = idx >> 5, j = idx & 31;
        double acc = (double)in_proj_b[32 + j];
        for (int d = 0; d < 32; ++d)
            acc += (double)expert_keys[s * 32 + d] * (double)in_proj_w[(32 + j) * 32 + d];
        Ksh[s][j] = acc;
    }
    // Q = embed_table @ Wq.T + bq
    for (int idx = tid; idx < NTASK * 32; idx += BLK) {
        int t = idx >> 5, j = idx & 31;
        double acc = (double)in_proj_b[j];
        for (int d = 0; d < 32; ++d)
            acc += (double)embed_table[t * 32 + d] * (double)in_proj_w[j * 32 + d];
        Qsh[t][j] = acc;
    }
    __syncthreads();

    // scores[t*4+h][s] = dot(Q[t][h*8..], K[s][h*8..]) / f32(sqrt(8))
    const double SCALE = 1.0 / (double)((float)2.8284271247461903);
    for (int idx = tid; idx < 24 * 32; idx += BLK) {
        int th = idx >> 5, s = idx & 31;
        int t = th >> 2, h = th & 3;
        double acc = 0.0;
        for (int d = 0; d < 8; ++d)
            acc += Qsh[t][h * 8 + d] * Ksh[s][h * 8 + d];
        sc[th][s] = acc * SCALE;
    }
    __syncthreads();
    if (tid < 24) {                      // cheap serial max per (t,h)
        double m = sc[tid][0];
        for (int s = 1; s < 32; ++s) m = fmax(m, sc[tid][s]);
        red[tid] = m;
    }
    __syncthreads();
    for (int idx = tid; idx < 24 * 32; idx += BLK) {   // parallel exp
        int th = idx >> 5, s = idx & 31;
        sc[th][s] = exp(sc[th][s] - red[th]);
    }
    __syncthreads();
    if (tid < 24) {                      // serial sum -> inv
        double sum = 0.0;
        for (int s = 0; s < 32; ++s) sum += sc[tid][s];
        red[tid] = 1.0 / sum;
    }
    __syncthreads();
    // attn = mean over h of softmax rows
    for (int idx = tid; idx < NTASK * 32; idx += BLK) {
        int t = idx >> 5, s = idx & 31;
        attn[t][s] = 0.25 * (sc[t*4+0][s]*red[t*4+0] + sc[t*4+1][s]*red[t*4+1]
                           + sc[t*4+2][s]*red[t*4+2] + sc[t*4+3][s]*red[t*4+3]);
    }
    __syncthreads();
    if (tid < NTASK) {
        double m = attn[tid][0];
        for (int s = 1; s < 32; ++s) m = fmax(m, attn[tid][s]);
        red2[tid] = m;
    }
    __syncthreads();
    for (int idx = tid; idx < NTASK * 32; idx += BLK) {
        int t = idx >> 5, s = idx & 31;
        ew[t][s] = exp(attn[t][s] - red2[t]);
    }
    __syncthreads();
    if (tid < NTASK) {
        double sum = 0.0;
        for (int s = 0; s < 32; ++s) sum += ew[tid][s];
        red2[tid] = 1.0 / sum;
    }
    __syncthreads();

    // cl / ns tables
    for (int idx = tid; idx < NTASK * NE; idx += BLK) {
        int t = idx >> 6, e = idx & 63;
        double inv = red2[t];
        double a  = (double)fc_gate_b[e];
        double n0 = (double)fc_noise_b[e];
        for (int d = 0; d < 32; ++d) {
            double w = ew[t][d] * inv;
            a  += w * (double)fc_gate_w [e * 32 + d];
            n0 += w * (double)fc_noise_w[e * 32 + d];
        }
        double sp = (n0 > 0.0) ? (n0 + log1p(exp(-n0))) : log1p(exp(n0));
        double ns = sp + 0.01;
        const int o = e * 8 + t;
        tab_f[o * 2 + 0] = (float)a;
        tab_f[o * 2 + 1] = (float)ns;
        tab_d[o] = make_double2(a, ns);
    }
    // defined values in unused t slots (6,7)
    for (int idx = tid; idx < 512; idx += BLK) {
        if ((idx & 7) >= NTASK) {
            tab_f[idx * 2 + 0] = 0.f;
            tab_f[idx * 2 + 1] = 0.f;
            tab_d[idx] = make_double2(0.0, 0.0);
        }
    }
}

// ---------------------------------------------------------------------------
// Kernel B: LDS-staged tile router. 256 rows/block, one row per thread.
// Coalesced global <-> LDS with XOR swizzle (col4 ^ (row&15)) so per-row
// ds_read_b128 at 256B stride is conflict-free.
// ---------------------------------------------------------------------------
__global__ __launch_bounds__(BLK) void router_kernel(
    const int*     __restrict__ taskID,
    const float*   __restrict__ noise,    // (B,64)
    const float*   __restrict__ tab_f,    // f32 {cl,ns} pairs, [e*8+t]
    const double2* __restrict__ tab_d,    // f64 {cl,ns} pairs, [e*8+t]
    float* __restrict__ gates,            // (B,64)
    float* __restrict__ load,             // (64,)
    int B)
{
    __shared__ float4  tile[TILE * 16];   // 64 KB noise/gates tile (swizzled)
    __shared__ float2  s_tabf[512];       // 4 KB
    __shared__ double2 s_tabd[512];       // 8 KB
    __shared__ float   s_load[NE];

    const int tid = threadIdx.x;
    const long long rowBase = (long long)blockIdx.x * TILE;
    const int b = (int)(rowBase + tid);
    int t = 0;
    if (b < B) t = taskID[b];             // issued early, overlaps staging

    {
        const float2* gf = (const float2*)tab_f;
        for (int i = tid; i < 512; i += BLK) {
            s_tabf[i] = gf[i];
            s_tabd[i] = tab_d[i];
        }
    }
    if (tid < NE) s_load[tid] = 0.f;

    // ---- stage noise tile: coalesced dwordx4, swizzled LDS store ----
    const float4* gsrc = (const float4*)noise + rowBase * 16;
    #pragma unroll
    for (int k = 0; k < 16; ++k) {
        const int f = tid + k * BLK;          // 0..4095 float4s
        const int row = f >> 4, c = f & 15;
        float4 v = make_float4(0.f, 0.f, 0.f, 0.f);
        if (rowBase + row < B) v = gsrc[f];
        tile[row * 16 + (c ^ (row & 15))] = v;
    }
    __syncthreads();

    // ---- per-row top-2 routing ----
    if (b < B) {
        const int sw = tid & 15;
        float4* myrow = &tile[tid * 16];

        float v1 = -INFINITY, v2 = -INFINITY, v3 = -INFINITY;
        int   i1 = 0, i2 = 0, i3 = 0;
        float n1 = 0.f, n2 = 0.f, n3 = 0.f;

        #pragma unroll
        for (int c = 0; c < 16; ++c) {
            const float4 nv = myrow[c ^ sw];
            const float na[4] = {nv.x, nv.y, nv.z, nv.w};
            #pragma unroll
            for (int j = 0; j < 4; ++j) {
                const int e = c * 4 + j;
                const float2 cn = s_tabf[e * 8 + t];
                // match np elementwise: round mul then add (no fma contraction)
                const float l = __fadd_rn(cn.x, __fmul_rn(na[j], cn.y));
                if (l > v1) {
                    v3 = v2; i3 = i2; n3 = n2;
                    v2 = v1; i2 = i1; n2 = n1;
                    v1 = l;  i1 = e;  n1 = na[j];
                } else if (l > v2) {
                    v3 = v2; i3 = i2; n3 = n2;
                    v2 = l;  i2 = e;  n2 = na[j];
                } else if (l > v3) {
                    v3 = l;  i3 = e;  n3 = na[j];
                }
            }
        }

        // f64 refine of the 3 candidates (exact ordering near ties)
        double2 ca = s_tabd[i1 * 8 + t]; double va = ca.x + (double)n1 * ca.y; int ia = i1;
        double2 cb = s_tabd[i2 * 8 + t]; double vb = cb.x + (double)n2 * cb.y; int ib = i2;
        double2 cc = s_tabd[i3 * 8 + t]; double vc = cc.x + (double)n3 * cc.y; int ic = i3;
        if (vb > va || (vb == va && ib < ia)) { double tv = va; va = vb; vb = tv; int ti = ia; ia = ib; ib = ti; }
        if (vc > va || (vc == va && ic < ia)) { double tv = va; va = vc; vc = tv; int ti = ia; ia = ic; ic = ti; }
        if (vc > vb || (vc == vb && ic < ib)) { double tv = vb; vb = vc; vc = tv; int ti = ib; ib = ic; ic = ti; }

        const double e2 = exp(vb - va);
        const double denom = 1.0 + e2;
        const float g1 = (float)(1.0 / denom);
        const float g2 = (float)(e2 / denom);

        // write gates row back into the tile (own row only; no race)
        #pragma unroll
        for (int c = 0; c < 16; ++c) {
            const int e0 = c * 4;
            float4 w;
            w.x = (e0 + 0 == ia) ? g1 : ((e0 + 0 == ib) ? g2 : 0.f);
            w.y = (e0 + 1 == ia) ? g1 : ((e0 + 1 == ib) ? g2 : 0.f);
            w.z = (e0 + 2 == ia) ? g1 : ((e0 + 2 == ib) ? g2 : 0.f);
            w.w = (e0 + 3 == ia) ? g1 : ((e0 + 3 == ib) ? g2 : 0.f);
            myrow[c ^ sw] = w;
        }
        atomicAdd(&s_load[ia], g1);
        atomicAdd(&s_load[ib], g2);
    }
    __syncthreads();

    // ---- coalesced gates store from LDS ----
    float4* gdst = (float4*)gates + rowBase * 16;
    #pragma unroll
    for (int k = 0; k < 16; ++k) {
        const int f = tid + k * BLK;
        const int row = f >> 4, c = f & 15;
        if (rowBase + row < B) gdst[f] = tile[row * 16 + (c ^ (row & 15))];
    }
    if (tid < NE) atomicAdd(&load[tid], s_load[tid]);
}

// ---------------------------------------------------------------------------
extern "C" void kernel_launch(void* const* d_in, const int* in_sizes, int n_in,
                              void* d_out, int out_size, void* d_ws, size_t ws_size,
                              hipStream_t stream) {
    const int*   taskID      = (const int*)  d_in[0];
    const float* embed_table = (const float*)d_in[1];
    const float* expert_keys = (const float*)d_in[2];
    const float* in_proj_w   = (const float*)d_in[3];
    const float* in_proj_b   = (const float*)d_in[4];
    const float* fc_gate_w   = (const float*)d_in[5];
    const float* fc_gate_b   = (const float*)d_in[6];
    const float* fc_noise_w  = (const float*)d_in[7];
    const float* fc_noise_b  = (const float*)d_in[8];
    const float* noise       = (const float*)d_in[9];

    const int B = in_sizes[0];

    float*   tab_f = (float*)d_ws;                    // 4 KB
    double2* tab_d = (double2*)((char*)d_ws + 4096);  // 8 KB

    float* gates = (float*)d_out;
    float* load  = gates + (size_t)B * NE;

    precompute_kernel<<<1, BLK, 0, stream>>>(embed_table, expert_keys, in_proj_w, in_proj_b,
                                             fc_gate_w, fc_gate_b, fc_noise_w, fc_noise_b,
                                             tab_f, tab_d, load);

    const int grid = (B + TILE - 1) / TILE;
    router_kernel<<<grid, BLK, 0, stream>>>(taskID, noise, tab_f, tab_d,
                                            gates, load, B);
}